// Round 2
// baseline (793.924 us; speedup 1.0000x reference)
//
#include <hip/hip_runtime.h>
#include <stdint.h>

#define N_NODES 16384
#define NHN 4096
#define DIM 1024
#define K2D 2048
#define E_TOT 65536
#define E_HH 8192
#define E_OO 40960
// type boundaries: [0,8192) hh, [8192,49152) oo, [49152,65536) ho

// LDS row stride (shorts) for 32-col bf16 tiles: 40 = 80 B keeps 16 B alignment
// and breaks the 64 B power-of-2 stride that caused 3.4e7 bank-conflict cycles.
#define LSTR 40

typedef __attribute__((ext_vector_type(4))) float f32x4;
typedef __attribute__((ext_vector_type(8))) short s16x8;

static __device__ __forceinline__ unsigned short f2bf(float f) {
  union { float f; unsigned u; } v; v.f = f;
  unsigned r = v.u + 0x7FFF + ((v.u >> 16) & 1);
  return (unsigned short)(r >> 16);
}
static __device__ __forceinline__ float bf2f(unsigned short u) {
  union { unsigned u; float f; } v; v.u = ((unsigned)u) << 16;
  return v.f;
}

// ---- K0a: cast n_f fp32 -> bf16 into A_node[n][0..1024) (row stride 2048) ----
__global__ __launch_bounds__(256) void k_cast_nf(const float* __restrict__ nf,
                                                 unsigned short* __restrict__ A) {
  int i = blockIdx.x * 256 + threadIdx.x;   // indexes float4 groups; 4194304 total
  float4 v = ((const float4*)nf)[i];
  int n = i >> 8;                // (i*4) / 1024
  int k = (i & 255) << 2;        // (i*4) % 1024
  ushort4 o;
  o.x = f2bf(v.x); o.y = f2bf(v.y); o.z = f2bf(v.z); o.w = f2bf(v.w);
  *(ushort4*)(A + (size_t)n * K2D + k) = o;
}

// ---- K0b: transpose W [2048][1024] fp32 -> Wt [1024][2048] bf16 (5 matrices) ----
__global__ __launch_bounds__(256) void k_transpose(const float* __restrict__ W0,
                                                   const float* __restrict__ W1,
                                                   const float* __restrict__ W2,
                                                   const float* __restrict__ W3,
                                                   const float* __restrict__ W4,
                                                   unsigned short* __restrict__ Wt) {
  int bid = blockIdx.x;
  int w = bid >> 11;             // 2048 tiles per matrix
  int tt = bid & 2047;
  int kt = tt & 63, jt = tt >> 6;
  const float* W = (w == 0) ? W0 : (w == 1) ? W1 : (w == 2) ? W2 : (w == 3) ? W3 : W4;
  unsigned short* dst = Wt + (size_t)w * (DIM * K2D);
  __shared__ float s[32][33];
  int c = threadIdx.x & 31, r0 = threadIdx.x >> 5;
#pragma unroll
  for (int i = 0; i < 4; ++i) {
    int r = r0 + i * 8;
    s[r][c] = W[(size_t)(kt * 32 + r) * DIM + jt * 32 + c];
  }
  __syncthreads();
#pragma unroll
  for (int i = 0; i < 4; ++i) {
    int r = r0 + i * 8;
    dst[(size_t)(jt * 32 + r) * K2D + kt * 32 + c] = f2bf(s[c][r]);
  }
}

// ---- K1: fused edge MLP + attention logit, one j-tile per block ----
// grid (8 jt, 512 eblk); jt fastest so the 8 blocks sharing an edge tile are
// dispatched adjacently -> their gathered A rows hit L3 instead of HBM 8x.
// logit[e] += sum_{j in tile} relu( feat[e].W[:,j] + b[j] ) * Wa[j]
__global__ __launch_bounds__(256) void k_edge_logit(
    const unsigned short* __restrict__ A,      // A_node [N][2048] bf16, cols 0..1023 = n_f
    const unsigned short* __restrict__ Wt_all, // 5 x [1024][2048] bf16
    const float* __restrict__ b_hh, const float* __restrict__ b_oo, const float* __restrict__ b_ho,
    const float* __restrict__ Wa,
    const int* __restrict__ esrc, const int* __restrict__ edst,
    float* __restrict__ logit) {
  const int t = threadIdx.x;
  const int jt = blockIdx.x;           // 0..7
  const int e0 = blockIdx.y * 128;
  const unsigned short* Wt;
  const float* bias;
  if (e0 < E_HH)              { Wt = Wt_all;                 bias = b_hh; }
  else if (e0 < E_HH + E_OO)  { Wt = Wt_all + 1 * 2097152;   bias = b_oo; }
  else                        { Wt = Wt_all + 2 * 2097152;   bias = b_ho; }

  __shared__ __align__(16) unsigned short sA[128 * LSTR];
  __shared__ __align__(16) unsigned short sB[128 * LSTR];
  __shared__ float sBias[128];
  __shared__ float sWa[128];
  __shared__ int sIdx[2][128];

  if (t < 128) {
    sBias[t] = bias[jt * 128 + t];
    sWa[t] = Wa[jt * 128 + t];
    sIdx[0][t] = esrc[e0 + t];
    sIdx[1][t] = edst[e0 + t];
  }
  __syncthreads();

  const int lane = t & 63, wid = t >> 6;
  const int quad = lane >> 4, l16 = lane & 15;
  const int mbase = (wid >> 1) * 64, nbase = (wid & 1) * 64;

  f32x4 acc[4][4];
#pragma unroll
  for (int a = 0; a < 4; ++a)
#pragma unroll
    for (int b = 0; b < 4; ++b) acc[a][b] = (f32x4){0.f, 0.f, 0.f, 0.f};

  for (int k0 = 0; k0 < K2D; k0 += 32) {
    const int half = k0 >> 10, kk = k0 & 1023;
#pragma unroll
    for (int p = 0; p < 2; ++p) {
      int seg = t + p * 256;
      int row = seg >> 2, c8 = (seg & 3) * 8;
      int idx = sIdx[half][row];
      uint4 va = *(const uint4*)(A + (size_t)idx * K2D + kk + c8);
      *(uint4*)(sA + row * LSTR + c8) = va;
      uint4 vb = *(const uint4*)(Wt + (size_t)(jt * 128 + row) * K2D + k0 + c8);
      *(uint4*)(sB + row * LSTR + c8) = vb;
    }
    __syncthreads();
    s16x8 af[4], bfr[4];
#pragma unroll
    for (int mt = 0; mt < 4; ++mt)
      af[mt] = *(const s16x8*)(sA + (mbase + mt * 16 + l16) * LSTR + quad * 8);
#pragma unroll
    for (int nt = 0; nt < 4; ++nt)
      bfr[nt] = *(const s16x8*)(sB + (nbase + nt * 16 + l16) * LSTR + quad * 8);
#pragma unroll
    for (int mt = 0; mt < 4; ++mt)
#pragma unroll
      for (int nt = 0; nt < 4; ++nt)
        acc[mt][nt] = __builtin_amdgcn_mfma_f32_16x16x32_bf16(af[mt], bfr[nt], acc[mt][nt], 0, 0, 0);
    __syncthreads();
  }

  // epilogue: relu(+bias) * Wa, reduce over this block's 128 cols -> partial logit
  float rowsum[4][4];
#pragma unroll
  for (int a = 0; a < 4; ++a)
#pragma unroll
    for (int b = 0; b < 4; ++b) rowsum[a][b] = 0.f;
#pragma unroll
  for (int nt = 0; nt < 4; ++nt) {
    int jl = nbase + nt * 16 + l16;
    float bj = sBias[jl], wj = sWa[jl];
#pragma unroll
    for (int mt = 0; mt < 4; ++mt)
#pragma unroll
      for (int r = 0; r < 4; ++r) {
        float v = acc[mt][nt][r] + bj;
        v = v > 0.f ? v : 0.f;
        rowsum[mt][r] += v * wj;
      }
  }
#pragma unroll
  for (int mt = 0; mt < 4; ++mt)
#pragma unroll
    for (int r = 0; r < 4; ++r) {
      float s = rowsum[mt][r];
      s += __shfl_xor(s, 1);
      s += __shfl_xor(s, 2);
      s += __shfl_xor(s, 4);
      s += __shfl_xor(s, 8);
      if (l16 == 0) {
        int m = mbase + mt * 16 + quad * 4 + r;
        atomicAdd(&logit[e0 + m], s);
      }
    }
}

// ---- K2: CSR build ----
__global__ __launch_bounds__(256) void k_count(const int* __restrict__ edst, int* __restrict__ counts) {
  int e = blockIdx.x * 256 + threadIdx.x;
  atomicAdd(&counts[edst[e]], 1);
}

__global__ __launch_bounds__(1024) void k_scan(const int* __restrict__ counts,
                                               int* __restrict__ offsets,
                                               int* __restrict__ cursor) {
  __shared__ int sT[1024];
  int t = threadIdx.x;
  int base = t * 16;
  int loc[16];
  int s = 0;
#pragma unroll
  for (int i = 0; i < 16; ++i) { loc[i] = s; s += counts[base + i]; }
  sT[t] = s;
  __syncthreads();
  for (int off = 1; off < 1024; off <<= 1) {
    int v = (t >= off) ? sT[t - off] : 0;
    __syncthreads();
    sT[t] += v;
    __syncthreads();
  }
  int excl = sT[t] - s;
#pragma unroll
  for (int i = 0; i < 16; ++i) {
    int o = excl + loc[i];
    offsets[base + i] = o;
    cursor[base + i] = o;
  }
  if (t == 1023) offsets[N_NODES] = sT[1023];
}

__global__ __launch_bounds__(256) void k_fill(const int* __restrict__ edst,
                                              int* __restrict__ cursor,
                                              int* __restrict__ eord) {
  int e = blockIdx.x * 256 + threadIdx.x;
  int p = atomicAdd(&cursor[edst[e]], 1);
  eord[p] = e;
}

// ---- K3: per-node softmax + weighted aggregation -> z half of A_node (bf16) ----
__global__ __launch_bounds__(256) void k_aggregate(const int* __restrict__ offsets,
                                                   const int* __restrict__ eord,
                                                   const float* __restrict__ logit,
                                                   const int* __restrict__ esrc,
                                                   unsigned short* __restrict__ A) {
  int n = blockIdx.x, t = threadIdx.x;
  int off = offsets[n], end = offsets[n + 1];
  float a0 = 0.f, a1 = 0.f, a2 = 0.f, a3 = 0.f;
  if (end > off) {
    float den = 0.f;
    for (int i = off; i < end; ++i) den += __expf(logit[eord[i]]);
    float rden = 1.0f / den;
    for (int i = off; i < end; ++i) {
      int e = eord[i];
      float al = __expf(logit[e]) * rden;
      int s = esrc[e];
      ushort4 v = *(const ushort4*)(A + (size_t)s * K2D + t * 4);
      a0 += al * bf2f(v.x);
      a1 += al * bf2f(v.y);
      a2 += al * bf2f(v.z);
      a3 += al * bf2f(v.w);
    }
  }
  ushort4 o;
  o.x = f2bf(a0); o.y = f2bf(a1); o.z = f2bf(a2); o.w = f2bf(a3);
  *(ushort4*)(A + (size_t)n * K2D + DIM + t * 4) = o;
}

// ---- K4: node MLP GEMM: out = relu(A_node @ Wt_node^T + b), fp32 out ----
// grid (8 jt, 128 mblk); jt fastest so same-m0 blocks share A tiles in L2/L3.
__global__ __launch_bounds__(256) void k_node_gemm(
    const unsigned short* __restrict__ A,
    const unsigned short* __restrict__ Wt_hn, const unsigned short* __restrict__ Wt_on,
    const float* __restrict__ b_hn, const float* __restrict__ b_on,
    float* __restrict__ out) {
  const int jt = blockIdx.x;
  const int m0 = blockIdx.y * 128;
  const unsigned short* Wt = (m0 < NHN) ? Wt_hn : Wt_on;
  const float* bias = (m0 < NHN) ? b_hn : b_on;
  __shared__ __align__(16) unsigned short sA[128 * LSTR];
  __shared__ __align__(16) unsigned short sB[128 * LSTR];
  __shared__ float sBias[128];
  int t = threadIdx.x;
  if (t < 128) sBias[t] = bias[jt * 128 + t];
  const int lane = t & 63, wid = t >> 6;
  const int quad = lane >> 4, l16 = lane & 15;
  const int mbase = (wid >> 1) * 64, nbase = (wid & 1) * 64;
  f32x4 acc[4][4];
#pragma unroll
  for (int a = 0; a < 4; ++a)
#pragma unroll
    for (int b = 0; b < 4; ++b) acc[a][b] = (f32x4){0.f, 0.f, 0.f, 0.f};
  __syncthreads();
  for (int k0 = 0; k0 < K2D; k0 += 32) {
#pragma unroll
    for (int p = 0; p < 2; ++p) {
      int seg = t + p * 256;
      int row = seg >> 2, c8 = (seg & 3) * 8;
      *(uint4*)(sA + row * LSTR + c8) = *(const uint4*)(A + (size_t)(m0 + row) * K2D + k0 + c8);
      *(uint4*)(sB + row * LSTR + c8) = *(const uint4*)(Wt + (size_t)(jt * 128 + row) * K2D + k0 + c8);
    }
    __syncthreads();
    s16x8 af[4], bfr[4];
#pragma unroll
    for (int mt = 0; mt < 4; ++mt)
      af[mt] = *(const s16x8*)(sA + (mbase + mt * 16 + l16) * LSTR + quad * 8);
#pragma unroll
    for (int nt = 0; nt < 4; ++nt)
      bfr[nt] = *(const s16x8*)(sB + (nbase + nt * 16 + l16) * LSTR + quad * 8);
#pragma unroll
    for (int mt = 0; mt < 4; ++mt)
#pragma unroll
      for (int nt = 0; nt < 4; ++nt)
        acc[mt][nt] = __builtin_amdgcn_mfma_f32_16x16x32_bf16(af[mt], bfr[nt], acc[mt][nt], 0, 0, 0);
    __syncthreads();
  }
#pragma unroll
  for (int nt = 0; nt < 4; ++nt) {
    int jl = nbase + nt * 16 + l16;
    float bj = sBias[jl];
    int j = jt * 128 + jl;
#pragma unroll
    for (int mt = 0; mt < 4; ++mt)
#pragma unroll
      for (int r = 0; r < 4; ++r) {
        float v = acc[mt][nt][r] + bj;
        v = v > 0.f ? v : 0.f;
        int m = m0 + mbase + mt * 16 + quad * 4 + r;
        out[(size_t)m * DIM + j] = v;
      }
  }
}

// ---- workspace layout (bytes) ----
//   A_node : 0          .. 67108864   [16384][2048] bf16 (cols 0..1023 n_f, 1024..2047 z_f)
//   Wt     : 67108864   .. 88080384   5 x [1024][2048] bf16 (hh, oo, ho, hn, on)
//   logit  : 88080384   .. 88342528   [65536] f32
//   counts : 88342528   .. 88408064   [16384] i32
//   offsets: 88408064   .. 88473856   [16385] i32 (+pad)
//   cursor : 88473856   .. 88539392   [16384] i32
//   eord   : 88539392   .. 88801536   [65536] i32
extern "C" void kernel_launch(void* const* d_in, const int* in_sizes, int n_in,
                              void* d_out, int out_size, void* d_ws, size_t ws_size,
                              hipStream_t stream) {
  const float* n_f  = (const float*)d_in[0];
  const float* W_hh = (const float*)d_in[1];
  const float* b_hh = (const float*)d_in[2];
  const float* W_oo = (const float*)d_in[3];
  const float* b_oo = (const float*)d_in[4];
  const float* W_ho = (const float*)d_in[5];
  const float* b_ho = (const float*)d_in[6];
  const float* W_a  = (const float*)d_in[7];
  // d_in[8] = b_a : dropped (uniform shift cancels in segment softmax)
  const float* W_hn = (const float*)d_in[9];
  const float* b_hn = (const float*)d_in[10];
  const float* W_on = (const float*)d_in[11];
  const float* b_on = (const float*)d_in[12];
  const int* esrc = (const int*)d_in[13];
  const int* edst = (const int*)d_in[14];
  float* out = (float*)d_out;

  char* ws = (char*)d_ws;
  unsigned short* A_node = (unsigned short*)(ws);
  unsigned short* Wt     = (unsigned short*)(ws + 67108864);
  float* logit  = (float*)(ws + 88080384);
  int* counts   = (int*)(ws + 88342528);
  int* offsets  = (int*)(ws + 88408064);
  int* cursor   = (int*)(ws + 88473856);
  int* eord     = (int*)(ws + 88539392);

  // zero logit + counts (contiguous)
  hipMemsetAsync(ws + 88080384, 0, 262144 + 65536, stream);

  k_cast_nf<<<16384, 256, 0, stream>>>(n_f, A_node);
  k_transpose<<<5 * 2048, 256, 0, stream>>>(W_hh, W_oo, W_ho, W_hn, W_on, Wt);
  k_edge_logit<<<dim3(8, E_TOT / 128), 256, 0, stream>>>(A_node, Wt, b_hh, b_oo, b_ho, W_a, esrc, edst, logit);
  k_count<<<E_TOT / 256, 256, 0, stream>>>(edst, counts);
  k_scan<<<1, 1024, 0, stream>>>(counts, offsets, cursor);
  k_fill<<<E_TOT / 256, 256, 0, stream>>>(edst, cursor, eord);
  k_aggregate<<<N_NODES, 256, 0, stream>>>(offsets, eord, logit, esrc, A_node);
  k_node_gemm<<<dim3(8, N_NODES / 128), 256, 0, stream>>>(
      A_node, Wt + 3 * 2097152, Wt + 4 * 2097152, b_hn, b_on, out);
}

// Round 3
// 745.746 us; speedup vs baseline: 1.0646x; 1.0646x over previous
//
#include <hip/hip_runtime.h>
#include <stdint.h>

#define N_NODES 16384
#define NHN 4096
#define DIM 1024
#define K2D 2048
#define E_TOT 65536
#define E_HH 8192
#define E_OO 40960
// type boundaries: [0,8192) hh, [8192,49152) oo, [49152,65536) ho

typedef __attribute__((ext_vector_type(4))) float f32x4;
typedef __attribute__((ext_vector_type(8))) short s16x8;

static __device__ __forceinline__ unsigned short f2bf(float f) {
  union { float f; unsigned u; } v; v.f = f;
  unsigned r = v.u + 0x7FFF + ((v.u >> 16) & 1);
  return (unsigned short)(r >> 16);
}
static __device__ __forceinline__ float bf2f(unsigned short u) {
  union { unsigned u; float f; } v; v.u = ((unsigned)u) << 16;
  return v.f;
}

// async 16B global -> LDS (direct, no VGPR round trip). LDS side must be
// wave-uniform base + lane*16; global side may be a per-lane (gather) address.
static __device__ __forceinline__ void async16(const unsigned short* g, unsigned short* l) {
  __builtin_amdgcn_global_load_lds(
      (const __attribute__((address_space(1))) unsigned int*)g,
      (__attribute__((address_space(3))) unsigned int*)l,
      16, 0, 0);
}

// ---- K0a: cast n_f fp32 -> bf16 into A_node[n][0..1024) (row stride 2048) ----
__global__ __launch_bounds__(256) void k_cast_nf(const float* __restrict__ nf,
                                                 unsigned short* __restrict__ A) {
  int i = blockIdx.x * 256 + threadIdx.x;   // indexes float4 groups; 4194304 total
  float4 v = ((const float4*)nf)[i];
  int n = i >> 8;                // (i*4) / 1024
  int k = (i & 255) << 2;        // (i*4) % 1024
  ushort4 o;
  o.x = f2bf(v.x); o.y = f2bf(v.y); o.z = f2bf(v.z); o.w = f2bf(v.w);
  *(ushort4*)(A + (size_t)n * K2D + k) = o;
}

// ---- K0b: transpose W [2048][1024] fp32 -> Wt [1024][2048] bf16 (5 matrices) ----
__global__ __launch_bounds__(256) void k_transpose(const float* __restrict__ W0,
                                                   const float* __restrict__ W1,
                                                   const float* __restrict__ W2,
                                                   const float* __restrict__ W3,
                                                   const float* __restrict__ W4,
                                                   unsigned short* __restrict__ Wt) {
  int bid = blockIdx.x;
  int w = bid >> 11;             // 2048 tiles per matrix
  int tt = bid & 2047;
  int kt = tt & 63, jt = tt >> 6;
  const float* W = (w == 0) ? W0 : (w == 1) ? W1 : (w == 2) ? W2 : (w == 3) ? W3 : W4;
  unsigned short* dst = Wt + (size_t)w * (DIM * K2D);
  __shared__ float s[32][33];
  int c = threadIdx.x & 31, r0 = threadIdx.x >> 5;
#pragma unroll
  for (int i = 0; i < 4; ++i) {
    int r = r0 + i * 8;
    s[r][c] = W[(size_t)(kt * 32 + r) * DIM + jt * 32 + c];
  }
  __syncthreads();
#pragma unroll
  for (int i = 0; i < 4; ++i) {
    int r = r0 + i * 8;
    dst[(size_t)(jt * 32 + r) * K2D + kt * 32 + c] = f2bf(s[c][r]);
  }
}

// ---- K1: fused edge MLP + attention logit, one j-tile per block ----
// grid (8 jt, 512 eblk). m97 staging: global_load_lds width=16, LSTR=32 (no
// pad -- required by the wave-uniform LDS constraint), per-thread register
// base pointers for the gathered src/dst rows (K-loop split src/dst halves).
// logit[e] += sum_{j in tile} relu( feat[e].W[:,j] + b[j] ) * Wa[j]
__global__ __launch_bounds__(256) void k_edge_logit(
    const unsigned short* __restrict__ A,      // A_node [N][2048] bf16, cols 0..1023 = n_f
    const unsigned short* __restrict__ Wt_all, // 5 x [1024][2048] bf16
    const float* __restrict__ b_hh, const float* __restrict__ b_oo, const float* __restrict__ b_ho,
    const float* __restrict__ Wa,
    const int* __restrict__ esrc, const int* __restrict__ edst,
    float* __restrict__ logit) {
  const int t = threadIdx.x;
  const int jt = blockIdx.x;           // 0..7
  const int e0 = blockIdx.y * 128;
  const unsigned short* Wt;
  const float* bias;
  if (e0 < E_HH)              { Wt = Wt_all;                 bias = b_hh; }
  else if (e0 < E_HH + E_OO)  { Wt = Wt_all + 1 * 2097152;   bias = b_oo; }
  else                        { Wt = Wt_all + 2 * 2097152;   bias = b_ho; }

  __shared__ __align__(16) unsigned short sA[128 * 32];
  __shared__ __align__(16) unsigned short sB[128 * 32];
  __shared__ float sBias[128];
  __shared__ float sWa[128];

  if (t < 128) {
    sBias[t] = bias[jt * 128 + t];
    sWa[t] = Wa[jt * 128 + t];
  }

  // staging coords: p in {0,1}: seg = t + p*256, row = seg>>2, col8 = (seg&3)*8
  const int row0 = t >> 2;             // 0..63  (p=0); p=1 row = row0+64
  const int c8 = (t & 3) * 8;
  const int s0 = esrc[e0 + row0], s1 = esrc[e0 + row0 + 64];
  const int d0 = edst[e0 + row0], d1 = edst[e0 + row0 + 64];
  const unsigned short* pS0 = A + (size_t)s0 * K2D + c8;
  const unsigned short* pS1 = A + (size_t)s1 * K2D + c8;
  const unsigned short* pD0 = A + (size_t)d0 * K2D + c8;
  const unsigned short* pD1 = A + (size_t)d1 * K2D + c8;
  const unsigned short* pB0 = Wt + (size_t)(jt * 128 + row0) * K2D + c8;
  const unsigned short* pB1 = pB0 + (size_t)64 * K2D;
  unsigned short* lA0 = sA + t * 8;          // byte offset t*16
  unsigned short* lA1 = lA0 + 2048;          // +4096 B
  unsigned short* lB0 = sB + t * 8;
  unsigned short* lB1 = lB0 + 2048;

  const int lane = t & 63, wid = t >> 6;
  const int quad = lane >> 4, l16 = lane & 15;
  const int mbase = (wid >> 1) * 64, nbase = (wid & 1) * 64;

  f32x4 acc[4][4];
#pragma unroll
  for (int a = 0; a < 4; ++a)
#pragma unroll
    for (int b = 0; b < 4; ++b) acc[a][b] = (f32x4){0.f, 0.f, 0.f, 0.f};

#pragma unroll 1
  for (int k0 = 0; k0 < K2D; k0 += 32) {
    // k<1024: src rows; k>=1024: dst rows (cols 0..1023 of the dst node)
    const unsigned short* a0 = (k0 < 1024) ? (pS0 + k0) : (pD0 + (k0 - 1024));
    const unsigned short* a1 = (k0 < 1024) ? (pS1 + k0) : (pD1 + (k0 - 1024));
    async16(a0, lA0);
    async16(a1, lA1);
    async16(pB0 + k0, lB0);
    async16(pB1 + k0, lB1);
    __syncthreads();
    s16x8 af[4], bfr[4];
#pragma unroll
    for (int mt = 0; mt < 4; ++mt)
      af[mt] = *(const s16x8*)(sA + (mbase + mt * 16 + l16) * 32 + quad * 8);
#pragma unroll
    for (int nt = 0; nt < 4; ++nt)
      bfr[nt] = *(const s16x8*)(sB + (nbase + nt * 16 + l16) * 32 + quad * 8);
#pragma unroll
    for (int mt = 0; mt < 4; ++mt)
#pragma unroll
      for (int nt = 0; nt < 4; ++nt)
        acc[mt][nt] = __builtin_amdgcn_mfma_f32_16x16x32_bf16(af[mt], bfr[nt], acc[mt][nt], 0, 0, 0);
    __syncthreads();
  }

  // epilogue: relu(+bias) * Wa, reduce over this block's 128 cols -> partial logit
  float rowsum[4][4];
#pragma unroll
  for (int a = 0; a < 4; ++a)
#pragma unroll
    for (int b = 0; b < 4; ++b) rowsum[a][b] = 0.f;
#pragma unroll
  for (int nt = 0; nt < 4; ++nt) {
    int jl = nbase + nt * 16 + l16;
    float bj = sBias[jl], wj = sWa[jl];
#pragma unroll
    for (int mt = 0; mt < 4; ++mt)
#pragma unroll
      for (int r = 0; r < 4; ++r) {
        float v = acc[mt][nt][r] + bj;
        v = v > 0.f ? v : 0.f;
        rowsum[mt][r] += v * wj;
      }
  }
#pragma unroll
  for (int mt = 0; mt < 4; ++mt)
#pragma unroll
    for (int r = 0; r < 4; ++r) {
      float s = rowsum[mt][r];
      s += __shfl_xor(s, 1);
      s += __shfl_xor(s, 2);
      s += __shfl_xor(s, 4);
      s += __shfl_xor(s, 8);
      if (l16 == 0) {
        int m = mbase + mt * 16 + quad * 4 + r;
        atomicAdd(&logit[e0 + m], s);
      }
    }
}

// ---- K2: CSR build ----
__global__ __launch_bounds__(256) void k_count(const int* __restrict__ edst, int* __restrict__ counts) {
  int e = blockIdx.x * 256 + threadIdx.x;
  atomicAdd(&counts[edst[e]], 1);
}

__global__ __launch_bounds__(1024) void k_scan(const int* __restrict__ counts,
                                               int* __restrict__ offsets,
                                               int* __restrict__ cursor) {
  __shared__ int sT[1024];
  int t = threadIdx.x;
  int base = t * 16;
  int loc[16];
  int s = 0;
#pragma unroll
  for (int i = 0; i < 16; ++i) { loc[i] = s; s += counts[base + i]; }
  sT[t] = s;
  __syncthreads();
  for (int off = 1; off < 1024; off <<= 1) {
    int v = (t >= off) ? sT[t - off] : 0;
    __syncthreads();
    sT[t] += v;
    __syncthreads();
  }
  int excl = sT[t] - s;
#pragma unroll
  for (int i = 0; i < 16; ++i) {
    int o = excl + loc[i];
    offsets[base + i] = o;
    cursor[base + i] = o;
  }
  if (t == 1023) offsets[N_NODES] = sT[1023];
}

__global__ __launch_bounds__(256) void k_fill(const int* __restrict__ edst,
                                              int* __restrict__ cursor,
                                              int* __restrict__ eord) {
  int e = blockIdx.x * 256 + threadIdx.x;
  int p = atomicAdd(&cursor[edst[e]], 1);
  eord[p] = e;
}

// ---- K3: per-node softmax + weighted aggregation -> z half of A_node (bf16) ----
__global__ __launch_bounds__(256) void k_aggregate(const int* __restrict__ offsets,
                                                   const int* __restrict__ eord,
                                                   const float* __restrict__ logit,
                                                   const int* __restrict__ esrc,
                                                   unsigned short* __restrict__ A) {
  int n = blockIdx.x, t = threadIdx.x;
  int off = offsets[n], end = offsets[n + 1];
  float a0 = 0.f, a1 = 0.f, a2 = 0.f, a3 = 0.f;
  if (end > off) {
    float den = 0.f;
    for (int i = off; i < end; ++i) den += __expf(logit[eord[i]]);
    float rden = 1.0f / den;
    for (int i = off; i < end; ++i) {
      int e = eord[i];
      float al = __expf(logit[e]) * rden;
      int s = esrc[e];
      ushort4 v = *(const ushort4*)(A + (size_t)s * K2D + t * 4);
      a0 += al * bf2f(v.x);
      a1 += al * bf2f(v.y);
      a2 += al * bf2f(v.z);
      a3 += al * bf2f(v.w);
    }
  }
  ushort4 o;
  o.x = f2bf(a0); o.y = f2bf(a1); o.z = f2bf(a2); o.w = f2bf(a3);
  *(ushort4*)(A + (size_t)n * K2D + DIM + t * 4) = o;
}

// ---- K4: node MLP GEMM: out = relu(A_node @ Wt_node^T + b), fp32 out ----
// grid (8 jt, 128 mblk); m97 staging as in k_edge_logit.
__global__ __launch_bounds__(256) void k_node_gemm(
    const unsigned short* __restrict__ A,
    const unsigned short* __restrict__ Wt_hn, const unsigned short* __restrict__ Wt_on,
    const float* __restrict__ b_hn, const float* __restrict__ b_on,
    float* __restrict__ out) {
  const int jt = blockIdx.x;
  const int m0 = blockIdx.y * 128;
  const unsigned short* Wt = (m0 < NHN) ? Wt_hn : Wt_on;
  const float* bias = (m0 < NHN) ? b_hn : b_on;
  __shared__ __align__(16) unsigned short sA[128 * 32];
  __shared__ __align__(16) unsigned short sB[128 * 32];
  __shared__ float sBias[128];
  int t = threadIdx.x;
  if (t < 128) sBias[t] = bias[jt * 128 + t];

  const int row0 = t >> 2;
  const int c8 = (t & 3) * 8;
  const unsigned short* pA0 = A + (size_t)(m0 + row0) * K2D + c8;
  const unsigned short* pA1 = pA0 + (size_t)64 * K2D;
  const unsigned short* pB0 = Wt + (size_t)(jt * 128 + row0) * K2D + c8;
  const unsigned short* pB1 = pB0 + (size_t)64 * K2D;
  unsigned short* lA0 = sA + t * 8;
  unsigned short* lA1 = lA0 + 2048;
  unsigned short* lB0 = sB + t * 8;
  unsigned short* lB1 = lB0 + 2048;

  const int lane = t & 63, wid = t >> 6;
  const int quad = lane >> 4, l16 = lane & 15;
  const int mbase = (wid >> 1) * 64, nbase = (wid & 1) * 64;
  f32x4 acc[4][4];
#pragma unroll
  for (int a = 0; a < 4; ++a)
#pragma unroll
    for (int b = 0; b < 4; ++b) acc[a][b] = (f32x4){0.f, 0.f, 0.f, 0.f};

#pragma unroll 1
  for (int k0 = 0; k0 < K2D; k0 += 32) {
    async16(pA0 + k0, lA0);
    async16(pA1 + k0, lA1);
    async16(pB0 + k0, lB0);
    async16(pB1 + k0, lB1);
    __syncthreads();
    s16x8 af[4], bfr[4];
#pragma unroll
    for (int mt = 0; mt < 4; ++mt)
      af[mt] = *(const s16x8*)(sA + (mbase + mt * 16 + l16) * 32 + quad * 8);
#pragma unroll
    for (int nt = 0; nt < 4; ++nt)
      bfr[nt] = *(const s16x8*)(sB + (nbase + nt * 16 + l16) * 32 + quad * 8);
#pragma unroll
    for (int mt = 0; mt < 4; ++mt)
#pragma unroll
      for (int nt = 0; nt < 4; ++nt)
        acc[mt][nt] = __builtin_amdgcn_mfma_f32_16x16x32_bf16(af[mt], bfr[nt], acc[mt][nt], 0, 0, 0);
    __syncthreads();
  }
#pragma unroll
  for (int nt = 0; nt < 4; ++nt) {
    int jl = nbase + nt * 16 + l16;
    float bj = sBias[jl];
    int j = jt * 128 + jl;
#pragma unroll
    for (int mt = 0; mt < 4; ++mt)
#pragma unroll
      for (int r = 0; r < 4; ++r) {
        float v = acc[mt][nt][r] + bj;
        v = v > 0.f ? v : 0.f;
        int m = m0 + mbase + mt * 16 + quad * 4 + r;
        out[(size_t)m * DIM + j] = v;
      }
  }
}

// ---- workspace layout (bytes) ----
//   A_node : 0          .. 67108864   [16384][2048] bf16 (cols 0..1023 n_f, 1024..2047 z_f)
//   Wt     : 67108864   .. 88080384   5 x [1024][2048] bf16 (hh, oo, ho, hn, on)
//   logit  : 88080384   .. 88342528   [65536] f32
//   counts : 88342528   .. 88408064   [16384] i32
//   offsets: 88408064   .. 88473856   [16385] i32 (+pad)
//   cursor : 88473856   .. 88539392   [16384] i32
//   eord   : 88539392   .. 88801536   [65536] i32
extern "C" void kernel_launch(void* const* d_in, const int* in_sizes, int n_in,
                              void* d_out, int out_size, void* d_ws, size_t ws_size,
                              hipStream_t stream) {
  const float* n_f  = (const float*)d_in[0];
  const float* W_hh = (const float*)d_in[1];
  const float* b_hh = (const float*)d_in[2];
  const float* W_oo = (const float*)d_in[3];
  const float* b_oo = (const float*)d_in[4];
  const float* W_ho = (const float*)d_in[5];
  const float* b_ho = (const float*)d_in[6];
  const float* W_a  = (const float*)d_in[7];
  // d_in[8] = b_a : dropped (uniform shift cancels in segment softmax)
  const float* W_hn = (const float*)d_in[9];
  const float* b_hn = (const float*)d_in[10];
  const float* W_on = (const float*)d_in[11];
  const float* b_on = (const float*)d_in[12];
  const int* esrc = (const int*)d_in[13];
  const int* edst = (const int*)d_in[14];
  float* out = (float*)d_out;

  char* ws = (char*)d_ws;
  unsigned short* A_node = (unsigned short*)(ws);
  unsigned short* Wt     = (unsigned short*)(ws + 67108864);
  float* logit  = (float*)(ws + 88080384);
  int* counts   = (int*)(ws + 88342528);
  int* offsets  = (int*)(ws + 88408064);
  int* cursor   = (int*)(ws + 88473856);
  int* eord     = (int*)(ws + 88539392);

  // zero logit + counts (contiguous)
  hipMemsetAsync(ws + 88080384, 0, 262144 + 65536, stream);

  k_cast_nf<<<16384, 256, 0, stream>>>(n_f, A_node);
  k_transpose<<<5 * 2048, 256, 0, stream>>>(W_hh, W_oo, W_ho, W_hn, W_on, Wt);
  k_edge_logit<<<dim3(8, E_TOT / 128), 256, 0, stream>>>(A_node, Wt, b_hh, b_oo, b_ho, W_a, esrc, edst, logit);
  k_count<<<E_TOT / 256, 256, 0, stream>>>(edst, counts);
  k_scan<<<1, 1024, 0, stream>>>(counts, offsets, cursor);
  k_fill<<<E_TOT / 256, 256, 0, stream>>>(edst, cursor, eord);
  k_aggregate<<<N_NODES, 256, 0, stream>>>(offsets, eord, logit, esrc, A_node);
  k_node_gemm<<<dim3(8, N_NODES / 128), 256, 0, stream>>>(
      A_node, Wt + 3 * 2097152, Wt + 4 * 2097152, b_hn, b_on, out);
}

// Round 4
// 671.709 us; speedup vs baseline: 1.1819x; 1.1102x over previous
//
#include <hip/hip_runtime.h>
#include <stdint.h>

#define N_NODES 16384
#define NHN 4096
#define DIM 1024
#define K2D 2048
#define E_TOT 65536
#define E_HH 8192
#define E_OO 40960
// type boundaries: [0,8192) hh, [8192,49152) oo, [49152,65536) ho

typedef __attribute__((ext_vector_type(4))) float f32x4;
typedef __attribute__((ext_vector_type(8))) short s16x8;

static __device__ __forceinline__ unsigned short f2bf(float f) {
  union { float f; unsigned u; } v; v.f = f;
  unsigned r = v.u + 0x7FFF + ((v.u >> 16) & 1);
  return (unsigned short)(r >> 16);
}
static __device__ __forceinline__ float bf2f(unsigned short u) {
  union { unsigned u; float f; } v; v.u = ((unsigned)u) << 16;
  return v.f;
}

// async 16B global -> LDS. LDS side must be wave-uniform base + lane*16;
// global side may be per-lane (gather ok).
static __device__ __forceinline__ void async16(const unsigned short* g, unsigned short* l) {
  __builtin_amdgcn_global_load_lds(
      (const __attribute__((address_space(1))) unsigned int*)g,
      (__attribute__((address_space(3))) unsigned int*)l,
      16, 0, 0);
}

// Bank-conflict swizzle: LDS stays linear (async16 requires it); the GLOBAL
// 16B-chunk index is XOR-permuted within each 64B row so that the b128
// fragment reads land 2-way max (free). cg = c ^ (row&3) ^ ((row>>2)&3).
static __device__ __forceinline__ int swz(int c, int row) {
  return c ^ (row & 3) ^ ((row >> 2) & 3);
}

// ---- K0a: cast n_f fp32 -> bf16 into A_node[n][0..1024) (row stride 2048) ----
__global__ __launch_bounds__(256) void k_cast_nf(const float* __restrict__ nf,
                                                 unsigned short* __restrict__ A) {
  int i = blockIdx.x * 256 + threadIdx.x;   // 4194304 float4 groups
  float4 v = ((const float4*)nf)[i];
  int n = i >> 8;
  int k = (i & 255) << 2;
  ushort4 o;
  o.x = f2bf(v.x); o.y = f2bf(v.y); o.z = f2bf(v.z); o.w = f2bf(v.w);
  *(ushort4*)(A + (size_t)n * K2D + k) = o;
}

// ---- K0b: transpose W [2048][1024] fp32 -> Wt [1024][2048] bf16 (5 matrices) ----
__global__ __launch_bounds__(256) void k_transpose(const float* __restrict__ W0,
                                                   const float* __restrict__ W1,
                                                   const float* __restrict__ W2,
                                                   const float* __restrict__ W3,
                                                   const float* __restrict__ W4,
                                                   unsigned short* __restrict__ Wt) {
  int bid = blockIdx.x;
  int w = bid >> 11;
  int tt = bid & 2047;
  int kt = tt & 63, jt = tt >> 6;
  const float* W = (w == 0) ? W0 : (w == 1) ? W1 : (w == 2) ? W2 : (w == 3) ? W3 : W4;
  unsigned short* dst = Wt + (size_t)w * (DIM * K2D);
  __shared__ float s[32][33];
  int c = threadIdx.x & 31, r0 = threadIdx.x >> 5;
#pragma unroll
  for (int i = 0; i < 4; ++i) {
    int r = r0 + i * 8;
    s[r][c] = W[(size_t)(kt * 32 + r) * DIM + jt * 32 + c];
  }
  __syncthreads();
#pragma unroll
  for (int i = 0; i < 4; ++i) {
    int r = r0 + i * 8;
    dst[(size_t)(jt * 32 + r) * K2D + kt * 32 + c] = f2bf(s[c][r]);
  }
}

// ---- K1: fused edge MLP + attention logit. Tile = 64 edges x 512 cols ----
// grid (2 n-half, 1024 eblk), 256 threads (4 waves; wave w owns cols
// [w*128,(w+1)*128)). Full-N tile => each gathered edge row is fetched from
// L2/L3 ONCE (round-3 kernel refetched it 8x -> 883 MB L2-miss wall).
// logit[e] += sum_j relu(feat[e].W[:,j]+b[j]) * Wa[j]
__global__ __launch_bounds__(256, 2) void k_edge_logit(
    const unsigned short* __restrict__ A,      // A_node [N][2048] bf16
    const unsigned short* __restrict__ Wt_all, // 5 x [1024][2048] bf16
    const float* __restrict__ b_hh, const float* __restrict__ b_oo, const float* __restrict__ b_ho,
    const float* __restrict__ Wa,
    const int* __restrict__ esrc, const int* __restrict__ edst,
    float* __restrict__ logit) {
  const int t = threadIdx.x;
  const int half = blockIdx.x;         // 0..1 : 512-col half
  const int e0 = blockIdx.y * 64;
  const unsigned short* Wt;
  const float* bias;
  if (e0 < E_HH)              { Wt = Wt_all;                 bias = b_hh; }
  else if (e0 < E_HH + E_OO)  { Wt = Wt_all + 1 * 2097152;   bias = b_oo; }
  else                        { Wt = Wt_all + 2 * 2097152;   bias = b_ho; }
  const int n0 = half * 512;

  __shared__ __align__(16) unsigned short sA[64 * 32];    //  4 KB
  __shared__ __align__(16) unsigned short sB[512 * 32];   // 32 KB
  __shared__ float sBias[512];
  __shared__ float sWa[512];

  sBias[t] = bias[n0 + t];        sWa[t] = Wa[n0 + t];
  sBias[t + 256] = bias[n0 + t + 256]; sWa[t + 256] = Wa[n0 + t + 256];

  // staging: row0 = t>>2 (edge row / B row base), swizzled global chunk
  const int row0 = t >> 2;
  const int cg = swz(t & 3, row0) * 8;           // shorts offset in 64B row
  const int s0 = esrc[e0 + row0], d0 = edst[e0 + row0];
  const unsigned short* pS = A + (size_t)s0 * K2D + cg;
  const unsigned short* pD = A + (size_t)d0 * K2D + cg;
  const unsigned short* pB = Wt + (size_t)(n0 + row0) * K2D + cg;
  unsigned short* lA = sA + t * 8;
  unsigned short* lB = sB + t * 8;

  const int lane = t & 63, wid = t >> 6;
  const int quad = lane >> 4, l16 = lane & 15;
  const int cs = swz(quad, l16) * 8;             // frag-read chunk (shorts)

  f32x4 acc[4][8];
#pragma unroll
  for (int a = 0; a < 4; ++a)
#pragma unroll
    for (int b = 0; b < 8; ++b) acc[a][b] = (f32x4){0.f, 0.f, 0.f, 0.f};

#pragma unroll 1
  for (int k0 = 0; k0 < K2D; k0 += 32) {
    const unsigned short* ap = (k0 < 1024) ? (pS + k0) : (pD + (k0 - 1024));
    async16(ap, lA);
#pragma unroll
    for (int p = 0; p < 8; ++p)
      async16(pB + p * (64 * K2D) + k0, lB + p * 2048);
    __syncthreads();
    s16x8 af[4], bfr[8];
#pragma unroll
    for (int mt = 0; mt < 4; ++mt)
      af[mt] = *(const s16x8*)(sA + (mt * 16 + l16) * 32 + cs);
#pragma unroll
    for (int nt = 0; nt < 8; ++nt)
      bfr[nt] = *(const s16x8*)(sB + (wid * 128 + nt * 16 + l16) * 32 + cs);
#pragma unroll
    for (int mt = 0; mt < 4; ++mt)
#pragma unroll
      for (int nt = 0; nt < 8; ++nt)
        acc[mt][nt] = __builtin_amdgcn_mfma_f32_16x16x32_bf16(af[mt], bfr[nt], acc[mt][nt], 0, 0, 0);
    __syncthreads();
  }

  // epilogue: relu(+bias)*Wa, reduce over this wave's 128 cols, atomic partial
  float rowsum[4][4];
#pragma unroll
  for (int a = 0; a < 4; ++a)
#pragma unroll
    for (int b = 0; b < 4; ++b) rowsum[a][b] = 0.f;
#pragma unroll
  for (int nt = 0; nt < 8; ++nt) {
    int jl = wid * 128 + nt * 16 + l16;
    float bj = sBias[jl], wj = sWa[jl];
#pragma unroll
    for (int mt = 0; mt < 4; ++mt)
#pragma unroll
      for (int r = 0; r < 4; ++r) {
        float v = acc[mt][nt][r] + bj;
        v = v > 0.f ? v : 0.f;
        rowsum[mt][r] += v * wj;
      }
  }
#pragma unroll
  for (int mt = 0; mt < 4; ++mt)
#pragma unroll
    for (int r = 0; r < 4; ++r) {
      float s = rowsum[mt][r];
      s += __shfl_xor(s, 1);
      s += __shfl_xor(s, 2);
      s += __shfl_xor(s, 4);
      s += __shfl_xor(s, 8);
      if (l16 == 0) atomicAdd(&logit[e0 + mt * 16 + quad * 4 + r], s);
    }
}

// ---- K2: CSR build ----
__global__ __launch_bounds__(256) void k_count(const int* __restrict__ edst, int* __restrict__ counts) {
  int e = blockIdx.x * 256 + threadIdx.x;
  atomicAdd(&counts[edst[e]], 1);
}

__global__ __launch_bounds__(1024) void k_scan(const int* __restrict__ counts,
                                               int* __restrict__ offsets,
                                               int* __restrict__ cursor) {
  __shared__ int sT[1024];
  int t = threadIdx.x;
  int base = t * 16;
  int loc[16];
  int s = 0;
#pragma unroll
  for (int i = 0; i < 16; ++i) { loc[i] = s; s += counts[base + i]; }
  sT[t] = s;
  __syncthreads();
  for (int off = 1; off < 1024; off <<= 1) {
    int v = (t >= off) ? sT[t - off] : 0;
    __syncthreads();
    sT[t] += v;
    __syncthreads();
  }
  int excl = sT[t] - s;
#pragma unroll
  for (int i = 0; i < 16; ++i) {
    int o = excl + loc[i];
    offsets[base + i] = o;
    cursor[base + i] = o;
  }
  if (t == 1023) offsets[N_NODES] = sT[1023];
}

__global__ __launch_bounds__(256) void k_fill(const int* __restrict__ edst,
                                              int* __restrict__ cursor,
                                              int* __restrict__ eord) {
  int e = blockIdx.x * 256 + threadIdx.x;
  int p = atomicAdd(&cursor[edst[e]], 1);
  eord[p] = e;
}

// ---- K3: per-node softmax + weighted aggregation -> z half of A_node ----
__global__ __launch_bounds__(256) void k_aggregate(const int* __restrict__ offsets,
                                                   const int* __restrict__ eord,
                                                   const float* __restrict__ logit,
                                                   const int* __restrict__ esrc,
                                                   unsigned short* __restrict__ A) {
  int n = blockIdx.x, t = threadIdx.x;
  int off = offsets[n], end = offsets[n + 1];
  float a0 = 0.f, a1 = 0.f, a2 = 0.f, a3 = 0.f;
  if (end > off) {
    float den = 0.f;
    for (int i = off; i < end; ++i) den += __expf(logit[eord[i]]);
    float rden = 1.0f / den;
    for (int i = off; i < end; ++i) {
      int e = eord[i];
      float al = __expf(logit[e]) * rden;
      int s = esrc[e];
      ushort4 v = *(const ushort4*)(A + (size_t)s * K2D + t * 4);
      a0 += al * bf2f(v.x);
      a1 += al * bf2f(v.y);
      a2 += al * bf2f(v.z);
      a3 += al * bf2f(v.w);
    }
  }
  ushort4 o;
  o.x = f2bf(a0); o.y = f2bf(a1); o.z = f2bf(a2); o.w = f2bf(a3);
  *(ushort4*)(A + (size_t)n * K2D + DIM + t * 4) = o;
}

// ---- K4: node MLP GEMM, tile 64 x 512, full-N => A fetched once total ----
// grid (2 n-half, 256 mblk), 256 threads.
__global__ __launch_bounds__(256, 2) void k_node_gemm(
    const unsigned short* __restrict__ A,
    const unsigned short* __restrict__ Wt_hn, const unsigned short* __restrict__ Wt_on,
    const float* __restrict__ b_hn, const float* __restrict__ b_on,
    float* __restrict__ out) {
  const int t = threadIdx.x;
  const int half = blockIdx.x;
  const int m0 = blockIdx.y * 64;
  const unsigned short* Wt = (m0 < NHN) ? Wt_hn : Wt_on;
  const float* bias = (m0 < NHN) ? b_hn : b_on;
  const int n0 = half * 512;

  __shared__ __align__(16) unsigned short sA[64 * 32];
  __shared__ __align__(16) unsigned short sB[512 * 32];
  __shared__ float sBias[512];
  sBias[t] = bias[n0 + t];
  sBias[t + 256] = bias[n0 + t + 256];

  const int row0 = t >> 2;
  const int cg = swz(t & 3, row0) * 8;
  const unsigned short* pA = A + (size_t)(m0 + row0) * K2D + cg;
  const unsigned short* pB = Wt + (size_t)(n0 + row0) * K2D + cg;
  unsigned short* lA = sA + t * 8;
  unsigned short* lB = sB + t * 8;

  const int lane = t & 63, wid = t >> 6;
  const int quad = lane >> 4, l16 = lane & 15;
  const int cs = swz(quad, l16) * 8;

  f32x4 acc[4][8];
#pragma unroll
  for (int a = 0; a < 4; ++a)
#pragma unroll
    for (int b = 0; b < 8; ++b) acc[a][b] = (f32x4){0.f, 0.f, 0.f, 0.f};

#pragma unroll 1
  for (int k0 = 0; k0 < K2D; k0 += 32) {
    async16(pA + k0, lA);
#pragma unroll
    for (int p = 0; p < 8; ++p)
      async16(pB + p * (64 * K2D) + k0, lB + p * 2048);
    __syncthreads();
    s16x8 af[4], bfr[8];
#pragma unroll
    for (int mt = 0; mt < 4; ++mt)
      af[mt] = *(const s16x8*)(sA + (mt * 16 + l16) * 32 + cs);
#pragma unroll
    for (int nt = 0; nt < 8; ++nt)
      bfr[nt] = *(const s16x8*)(sB + (wid * 128 + nt * 16 + l16) * 32 + cs);
#pragma unroll
    for (int mt = 0; mt < 4; ++mt)
#pragma unroll
      for (int nt = 0; nt < 8; ++nt)
        acc[mt][nt] = __builtin_amdgcn_mfma_f32_16x16x32_bf16(af[mt], bfr[nt], acc[mt][nt], 0, 0, 0);
    __syncthreads();
  }
#pragma unroll
  for (int nt = 0; nt < 8; ++nt) {
    int jl = wid * 128 + nt * 16 + l16;
    float bj = sBias[jl];
    int j = n0 + jl;
#pragma unroll
    for (int mt = 0; mt < 4; ++mt)
#pragma unroll
      for (int r = 0; r < 4; ++r) {
        float v = acc[mt][nt][r] + bj;
        v = v > 0.f ? v : 0.f;
        int m = m0 + mt * 16 + quad * 4 + r;
        out[(size_t)m * DIM + j] = v;
      }
  }
}

// ---- workspace layout (bytes) ----
//   A_node : 0          .. 67108864   [16384][2048] bf16
//   Wt     : 67108864   .. 88080384   5 x [1024][2048] bf16 (hh, oo, ho, hn, on)
//   logit  : 88080384   .. 88342528   [65536] f32
//   counts : 88342528   .. 88408064   [16384] i32
//   offsets: 88408064   .. 88473856   [16385] i32 (+pad)
//   cursor : 88473856   .. 88539392   [16384] i32
//   eord   : 88539392   .. 88801536   [65536] i32
extern "C" void kernel_launch(void* const* d_in, const int* in_sizes, int n_in,
                              void* d_out, int out_size, void* d_ws, size_t ws_size,
                              hipStream_t stream) {
  const float* n_f  = (const float*)d_in[0];
  const float* W_hh = (const float*)d_in[1];
  const float* b_hh = (const float*)d_in[2];
  const float* W_oo = (const float*)d_in[3];
  const float* b_oo = (const float*)d_in[4];
  const float* W_ho = (const float*)d_in[5];
  const float* b_ho = (const float*)d_in[6];
  const float* W_a  = (const float*)d_in[7];
  // d_in[8] = b_a : dropped (uniform shift cancels in segment softmax)
  const float* W_hn = (const float*)d_in[9];
  const float* b_hn = (const float*)d_in[10];
  const float* W_on = (const float*)d_in[11];
  const float* b_on = (const float*)d_in[12];
  const int* esrc = (const int*)d_in[13];
  const int* edst = (const int*)d_in[14];
  float* out = (float*)d_out;

  char* ws = (char*)d_ws;
  unsigned short* A_node = (unsigned short*)(ws);
  unsigned short* Wt     = (unsigned short*)(ws + 67108864);
  float* logit  = (float*)(ws + 88080384);
  int* counts   = (int*)(ws + 88342528);
  int* offsets  = (int*)(ws + 88408064);
  int* cursor   = (int*)(ws + 88473856);
  int* eord     = (int*)(ws + 88539392);

  hipMemsetAsync(ws + 88080384, 0, 262144 + 65536, stream);

  k_cast_nf<<<16384, 256, 0, stream>>>(n_f, A_node);
  k_transpose<<<5 * 2048, 256, 0, stream>>>(W_hh, W_oo, W_ho, W_hn, W_on, Wt);
  k_edge_logit<<<dim3(2, E_TOT / 64), 256, 0, stream>>>(A_node, Wt, b_hh, b_oo, b_ho, W_a, esrc, edst, logit);
  k_count<<<E_TOT / 256, 256, 0, stream>>>(edst, counts);
  k_scan<<<1, 1024, 0, stream>>>(counts, offsets, cursor);
  k_fill<<<E_TOT / 256, 256, 0, stream>>>(edst, cursor, eord);
  k_aggregate<<<N_NODES, 256, 0, stream>>>(offsets, eord, logit, esrc, A_node);
  k_node_gemm<<<dim3(2, N_NODES / 64), 256, 0, stream>>>(
      A_node, Wt + 3 * 2097152, Wt + 4 * 2097152, b_hn, b_on, out);
}